// Round 8
// baseline (42.701 us; speedup 1.0000x reference)
//
#include <hip/hip_runtime.h>
#include <hip/hip_bf16.h>

#define NNZ   104858
#define NB    1024
#define NIN   1024
#define NOUT  1024

typedef __bf16 bf16;
typedef bf16  bf16x8  __attribute__((ext_vector_type(8)));
typedef float f32x16  __attribute__((ext_vector_type(16)));

// ---------------- pre: zero Wd | convert x->bf16 ----------------
__global__ __launch_bounds__(256)
void k_pre(const float* __restrict__ x, float* __restrict__ Wd,
           bf16* __restrict__ xb) {
    const int b = blockIdx.x, t = threadIdx.x;
    if (b < 512) {
        float4 z = {0.f, 0.f, 0.f, 0.f};
        float4* w4 = (float4*)Wd;
        int i = (b * 256 + t) * 2;
        w4[i] = z; w4[i + 1] = z;
    } else {
        const int base = ((b - 512) * 256 + t) * 8;
        const float4* s4 = (const float4*)(x + base);
        float4 v0 = s4[0], v1 = s4[1];
        bf16x8 o;
        o[0] = (bf16)v0.x; o[1] = (bf16)v0.y; o[2] = (bf16)v0.z; o[3] = (bf16)v0.w;
        o[4] = (bf16)v1.x; o[5] = (bf16)v1.y; o[6] = (bf16)v1.z; o[7] = (bf16)v1.w;
        *(bf16x8*)(xb + base) = o;
    }
}

// ---------------- densify: Wd[r][c] += w_k (f32 atomics; duplicates sum) ----
__global__ __launch_bounds__(256)
void k_densify(const int* __restrict__ idx, const float* __restrict__ w,
               float* __restrict__ Wd) {
    int k = blockIdx.x * 256 + threadIdx.x;
    if (k < NNZ) {
        int r = idx[k] & (NOUT - 1);
        int c = idx[NNZ + k] & (NIN - 1);
        atomicAdd(&Wd[r * NIN + c], w[k]);
    }
}

// ---------------- GEMM: out = x_bf16 * bf16(Wd)^T + bias ----------------
// Barrier-free wave-per-tile: each wave owns a 32x32 output tile, K=1024 in
// 64 steps of mfma_f32_32x32x16_bf16. A/B fragments loaded DIRECTLY from
// global (both K-contiguous): lane l reads 16B at row (l&31), k-offset
// (l>>5)*8. No LDS, no __syncthreads -> compiler software-pipelines freely.
// Block = 4 waves sharing one n-tile (B reads L1-hit across waves), covering
// m-rows msuper*128 + wave*32. XCD swizzle: xcd owns 4 n-tiles.
// C/D layout (HW-verified m74/m101): col=lane&31, row=(reg&3)+8*(reg>>2)+4*(lane>>5).
__global__ __launch_bounds__(256)
void k_gemm(const bf16* __restrict__ A, const float* __restrict__ Wd,
            const float* __restrict__ bias, float* __restrict__ out) {
    const int b     = blockIdx.x;
    const int xcd   = b & 7;
    const int local = b >> 3;                 // 0..31
    const int ntile = xcd * 4 + (local & 3);  // 0..31
    const int msup  = local >> 2;             // 0..7
    const int wave  = threadIdx.x >> 6;
    const int lane  = threadIdx.x & 63;

    const int m0 = msup * 128 + wave * 32;
    const int n0 = ntile * 32;
    const int lrow = lane & 31;
    const int lk   = (lane >> 5) * 8;

    const bf16*  ap = A  + (size_t)(m0 + lrow) * NIN + lk;
    const float* bp = Wd + (size_t)(n0 + lrow) * NIN + lk;

    f32x16 acc = {};

    #pragma unroll 8
    for (int ks = 0; ks < 64; ++ks) {
        bf16x8 av = *(const bf16x8*)(ap + ks * 16);
        float4 b0 = *(const float4*)(bp + ks * 16);
        float4 b1 = *(const float4*)(bp + ks * 16 + 4);
        bf16x8 bv;
        bv[0] = (bf16)b0.x; bv[1] = (bf16)b0.y; bv[2] = (bf16)b0.z; bv[3] = (bf16)b0.w;
        bv[4] = (bf16)b1.x; bv[5] = (bf16)b1.y; bv[6] = (bf16)b1.z; bv[7] = (bf16)b1.w;
        acc = __builtin_amdgcn_mfma_f32_32x32x16_bf16(av, bv, acc, 0, 0, 0);
    }

    const float bb = bias[n0 + lrow];
    const int rbase = m0 + 4 * (lane >> 5);
    #pragma unroll
    for (int reg = 0; reg < 16; ++reg) {
        int row = rbase + (reg & 3) + 8 * (reg >> 2);
        out[(size_t)row * NOUT + n0 + lrow] = acc[reg] + bb;
    }
}

// ---------------- launch ----------------
static inline size_t align256(size_t v) { return (v + 255) & ~(size_t)255; }

extern "C" void kernel_launch(void* const* d_in, const int* in_sizes, int n_in,
                              void* d_out, int out_size, void* d_ws, size_t ws_size,
                              hipStream_t stream) {
    const float* x    = (const float*)d_in[0];   // [NB][NIN]
    const float* wts  = (const float*)d_in[1];   // [NNZ]
    const float* bias = (const float*)d_in[2];   // [NOUT]
    const int*   idx  = (const int*)d_in[3];     // [2][NNZ] int32

    char* ws = (char*)d_ws;
    size_t off = 0;
    float* Wd = (float*)(ws + off); off = align256(off + (size_t)NOUT * NIN * 4);  // 4 MB
    bf16*  xb = (bf16*) (ws + off); off = align256(off + (size_t)NB * NIN * 2);    // 2 MB

    const int nb_nnz = (NNZ + 255) / 256;

    k_pre<<<1024, 256, 0, stream>>>(x, Wd, xb);
    k_densify<<<nb_nnz, 256, 0, stream>>>(idx, wts, Wd);
    k_gemm<<<256, 256, 0, stream>>>(xb, Wd, bias, (float*)d_out);
}

// Round 9
// 41.669 us; speedup vs baseline: 1.0248x; 1.0248x over previous
//
#include <hip/hip_runtime.h>
#include <hip/hip_bf16.h>

#define NNZ   104858
#define NB    1024
#define NIN   1024
#define NOUT  1024

typedef __bf16 bf16;
typedef bf16  bf16x8  __attribute__((ext_vector_type(8)));
typedef float f32x16  __attribute__((ext_vector_type(16)));

// ---------------- pre: zero Wd | convert x->bf16 ----------------
__global__ __launch_bounds__(256)
void k_pre(const float* __restrict__ x, float* __restrict__ Wd,
           bf16* __restrict__ xb) {
    const int b = blockIdx.x, t = threadIdx.x;
    if (b < 512) {
        float4 z = {0.f, 0.f, 0.f, 0.f};
        float4* w4 = (float4*)Wd;
        int i = (b * 256 + t) * 2;
        w4[i] = z; w4[i + 1] = z;
    } else {
        const int base = ((b - 512) * 256 + t) * 8;
        const float4* s4 = (const float4*)(x + base);
        float4 v0 = s4[0], v1 = s4[1];
        bf16x8 o;
        o[0] = (bf16)v0.x; o[1] = (bf16)v0.y; o[2] = (bf16)v0.z; o[3] = (bf16)v0.w;
        o[4] = (bf16)v1.x; o[5] = (bf16)v1.y; o[6] = (bf16)v1.z; o[7] = (bf16)v1.w;
        *(bf16x8*)(xb + base) = o;
    }
}

// ---------------- densify: Wd[r][c] += w_k (f32 atomics; duplicates sum) ----
__global__ __launch_bounds__(256)
void k_densify(const int* __restrict__ idx, const float* __restrict__ w,
               float* __restrict__ Wd) {
    int k = blockIdx.x * 256 + threadIdx.x;
    if (k < NNZ) {
        int r = idx[k] & (NOUT - 1);
        int c = idx[NNZ + k] & (NIN - 1);
        atomicAdd(&Wd[r * NIN + c], w[k]);
    }
}

// ---------------- GEMM: out = x_bf16 * bf16(Wd)^T + bias ----------------
// Barrier-free K-loop + in-block split-K=4. Block = 512 threads = 8 waves =
// 2 m-tiles x 4 K-quarters; each wave: 16 x mfma_f32_32x32x16_bf16 on its
// 32x32 tile / K in [kq*256,(kq+1)*256), A/B loaded straight global->VGPR
// (both K-contiguous; lane l: row l&31, k += (l>>5)*8). Grid 512 blocks =
// 2 blocks/CU = 4 waves/SIMD (TLP hides L2 latency; round-8 lesson).
// One barrier, then kq>0 publish partials to LDS (float2 stride: 2 lanes/bank
// = free), kq==0 waves fuse sum+bias+plain-store (single writer, replay-safe).
// C/D layout (HW-verified m74/m101): col=lane&31, row=(reg&3)+8*(reg>>2)+4*(lane>>5).
__global__ __launch_bounds__(512)
void k_gemm(const bf16* __restrict__ A, const float* __restrict__ Wd,
            const float* __restrict__ bias, float* __restrict__ out) {
    __shared__ float2 red[6][8][64];   // 24 KB: [pub-slot][reg-pair][lane]

    // XCD swizzle: xcd owns 4 consecutive n-tiles (B panel 512KB + A 2MB < L2)
    const int id    = blockIdx.x;
    const int xcd   = id & 7;
    const int local = id >> 3;                 // 0..63
    const int ntile = xcd * 4 + (local & 3);   // 0..31
    const int mpair = local >> 2;              // 0..15

    const int wv   = threadIdx.x >> 6;         // 0..7
    const int lane = threadIdx.x & 63;
    const int mt   = wv & 1;                   // m-tile within pair
    const int kq   = wv >> 1;                  // K quarter

    const int m0 = mpair * 64 + mt * 32;
    const int n0 = ntile * 32;
    const int lrow = lane & 31;
    const int lk   = (lane >> 5) * 8;

    const bf16*  ap = A  + (size_t)(m0 + lrow) * NIN + kq * 256 + lk;
    const float* bp = Wd + (size_t)(n0 + lrow) * NIN + kq * 256 + lk;

    f32x16 acc = {};

    #pragma unroll 8
    for (int ks = 0; ks < 16; ++ks) {
        bf16x8 av = *(const bf16x8*)(ap + ks * 16);
        float4 b0 = *(const float4*)(bp + ks * 16);
        float4 b1 = *(const float4*)(bp + ks * 16 + 4);
        bf16x8 bv;
        bv[0] = (bf16)b0.x; bv[1] = (bf16)b0.y; bv[2] = (bf16)b0.z; bv[3] = (bf16)b0.w;
        bv[4] = (bf16)b1.x; bv[5] = (bf16)b1.y; bv[6] = (bf16)b1.z; bv[7] = (bf16)b1.w;
        acc = __builtin_amdgcn_mfma_f32_32x32x16_bf16(av, bv, acc, 0, 0, 0);
    }

    if (kq > 0) {
        const int slot = (kq - 1) * 2 + mt;
        #pragma unroll
        for (int rp = 0; rp < 8; ++rp)
            red[slot][rp][lane] = make_float2(acc[2 * rp], acc[2 * rp + 1]);
    }
    __syncthreads();
    if (kq == 0) {
        #pragma unroll
        for (int rp = 0; rp < 8; ++rp) {
            float2 a0 = red[mt][rp][lane];
            float2 a1 = red[2 + mt][rp][lane];
            float2 a2 = red[4 + mt][rp][lane];
            acc[2 * rp]     += a0.x + a1.x + a2.x;
            acc[2 * rp + 1] += a0.y + a1.y + a2.y;
        }
        const float bb = bias[n0 + lrow];
        const int rbase = m0 + 4 * (lane >> 5);
        #pragma unroll
        for (int reg = 0; reg < 16; ++reg) {
            int row = rbase + (reg & 3) + 8 * (reg >> 2);
            out[(size_t)row * NOUT + n0 + lrow] = acc[reg] + bb;
        }
    }
}

// ---------------- launch ----------------
static inline size_t align256(size_t v) { return (v + 255) & ~(size_t)255; }

extern "C" void kernel_launch(void* const* d_in, const int* in_sizes, int n_in,
                              void* d_out, int out_size, void* d_ws, size_t ws_size,
                              hipStream_t stream) {
    const float* x    = (const float*)d_in[0];   // [NB][NIN]
    const float* wts  = (const float*)d_in[1];   // [NNZ]
    const float* bias = (const float*)d_in[2];   // [NOUT]
    const int*   idx  = (const int*)d_in[3];     // [2][NNZ] int32

    char* ws = (char*)d_ws;
    size_t off = 0;
    float* Wd = (float*)(ws + off); off = align256(off + (size_t)NOUT * NIN * 4);  // 4 MB
    bf16*  xb = (bf16*) (ws + off); off = align256(off + (size_t)NB * NIN * 2);    // 2 MB

    const int nb_nnz = (NNZ + 255) / 256;

    k_pre<<<1024, 256, 0, stream>>>(x, Wd, xb);
    k_densify<<<nb_nnz, 256, 0, stream>>>(idx, wts, Wd);
    k_gemm<<<512, 512, 0, stream>>>(xb, Wd, bias, (float*)d_out);
}